// Round 6
// baseline (736.680 us; speedup 1.0000x reference)
//
#include <hip/hip_runtime.h>
#include <hip/hip_bf16.h>

// ---------- types ----------
typedef __attribute__((ext_vector_type(8))) short short8;
typedef __attribute__((ext_vector_type(4))) float f32x4;

static __device__ __forceinline__ unsigned short f2bf(float x) {
  union { __hip_bfloat16 h; unsigned short u; } cv;
  cv.h = __float2bfloat16(x);
  return cv.u;
}

// ---------- cast fp32 -> bf16, up to 4 concatenated segments ----------
__global__ void cast4_kernel(const float* __restrict__ s0, long n0,
                             const float* __restrict__ s1, long n1,
                             const float* __restrict__ s2, long n2,
                             const float* __restrict__ s3, long n3,
                             unsigned short* __restrict__ dst) {
  long N4 = (n0 + n1 + n2 + n3) >> 2;
  for (long i = blockIdx.x * (long)blockDim.x + threadIdx.x; i < N4;
       i += (long)gridDim.x * blockDim.x) {
    long e = i << 2;
    const float* s; long j = e;
    if (j < n0) s = s0;
    else { j -= n0; if (j < n1) s = s1;
      else { j -= n1; if (j < n2) s = s2;
        else { j -= n2; s = s3; } } }
    float4 v = *reinterpret_cast<const float4*>(s + j);
    ushort4 o;
    o.x = f2bf(v.x); o.y = f2bf(v.y); o.z = f2bf(v.z); o.w = f2bf(v.w);
    *reinterpret_cast<ushort4*>(dst + e) = o;
  }
}

// ---------- descriptor NT GEMM: up to 4 branches selected by blockIdx.y range ----------
// 128x128 tile, m97 staging. A,B offsets = elements into arena U; C offsets =
// BYTES into arena Cb. outMode: 0=bf16, 1=fp32, 2=fp16. swiz: XCD z-chunk
// remap (requires gridDim.z % 8 == 0) — same-XCD blocks share few z-slices.
struct GD {
  long aOff[4], bOff[4], cOff[4];
  long sAb[4], sAh[4], sBb[4], sBh[4];
  long sC[4], ldc[4];
  int  lda[4], ldb[4], K[4], Hdiv[4];
  int  Mclamp[4], Nclamp[4], Mwrite[4], Nwrite[4];
  int  outMode[4], statsOff[4], Mvalid[4], Nvalid[4];
  float alpha[4];
  int  ystart[5];
  int  swiz;
};

__global__ __launch_bounds__(256)
void gemm_mega(const unsigned short* __restrict__ U, char* __restrict__ Cb,
               float* __restrict__ stats, GD d) {
  __shared__ unsigned short As[128 * 32];
  __shared__ unsigned short Bs[128 * 32];
  __shared__ float red[8];

  int bx = blockIdx.x, ybl = blockIdx.y, z = blockIdx.z;
  if (d.swiz) {
    int gx = gridDim.x, gy = gridDim.y;
    int flat = bx + gx * (ybl + gy * z);
    int xcd = flat & 7, slot = flat >> 3;
    int perz = gx * gy;
    int zl = slot / perz, rem = slot - zl * perz;
    z = xcd * (gridDim.z >> 3) + zl;
    ybl = rem / gx; bx = rem - ybl * gx;
  }
  int br = 0;
  while (ybl >= d.ystart[br + 1]) ++br;
  int m0 = (ybl - d.ystart[br]) * 128;
  int n0 = bx * 128;
  int Hd = d.Hdiv[br];
  int b = z / Hd, h = z - b * Hd;
  int K = d.K[br], lda = d.lda[br], ldb = d.ldb[br];
  const unsigned short* Ab = U + d.aOff[br] + (long)b * d.sAb[br] + (long)h * d.sAh[br];
  const unsigned short* Bb = U + d.bOff[br] + (long)b * d.sBb[br] + (long)h * d.sBh[br];

  int t = threadIdx.x, lane = t & 63, wave = t >> 6;
  int wm = (wave >> 1) * 64, wn = (wave & 1) * 64;
  int l15 = lane & 15, q = lane >> 4;
  int arow = t >> 2, acol = (t & 3) * 8;
  int rA0 = min(m0 + arow, d.Mclamp[br] - 1), rA1 = min(m0 + 64 + arow, d.Mclamp[br] - 1);
  int rB0 = min(n0 + arow, d.Nclamp[br] - 1), rB1 = min(n0 + 64 + arow, d.Nclamp[br] - 1);

  f32x4 acc[4][4] = {};
  for (int k0 = 0; k0 < K; k0 += 32) {
    __syncthreads();
    __builtin_amdgcn_global_load_lds(
        (const __attribute__((address_space(1))) void*)(Ab + (long)rA0 * lda + acol + k0),
        (__attribute__((address_space(3))) void*)(As + t * 8), 16, 0, 0);
    __builtin_amdgcn_global_load_lds(
        (const __attribute__((address_space(1))) void*)(Ab + (long)rA1 * lda + acol + k0),
        (__attribute__((address_space(3))) void*)(As + 2048 + t * 8), 16, 0, 0);
    __builtin_amdgcn_global_load_lds(
        (const __attribute__((address_space(1))) void*)(Bb + (long)rB0 * ldb + acol + k0),
        (__attribute__((address_space(3))) void*)(Bs + t * 8), 16, 0, 0);
    __builtin_amdgcn_global_load_lds(
        (const __attribute__((address_space(1))) void*)(Bb + (long)rB1 * ldb + acol + k0),
        (__attribute__((address_space(3))) void*)(Bs + 2048 + t * 8), 16, 0, 0);
    __syncthreads();
    short8 af[4], bfr[4];
#pragma unroll
    for (int i = 0; i < 4; ++i)
      af[i] = *reinterpret_cast<const short8*>(As + (wm + i * 16 + l15) * 32 + q * 8);
#pragma unroll
    for (int j = 0; j < 4; ++j)
      bfr[j] = *reinterpret_cast<const short8*>(Bs + (wn + j * 16 + l15) * 32 + q * 8);
#pragma unroll
    for (int i = 0; i < 4; ++i)
#pragma unroll
      for (int j = 0; j < 4; ++j)
        acc[i][j] = __builtin_amdgcn_mfma_f32_16x16x32_bf16(af[i], bfr[j], acc[i][j], 0, 0, 0);
  }

  float alpha = d.alpha[br];
  long cb = d.cOff[br];
  long ldc = d.ldc[br];
  long zc = (long)z * d.sC[br];
  int om = d.outMode[br];
  int Mw = d.Mwrite[br], Nw = d.Nwrite[br];
  int so = d.statsOff[br], Mv = d.Mvalid[br], Nv = d.Nvalid[br];
  float ssum = 0.f, ssq = 0.f;
#pragma unroll
  for (int i = 0; i < 4; ++i)
#pragma unroll
    for (int j = 0; j < 4; ++j)
#pragma unroll
      for (int r = 0; r < 4; ++r) {
        float v = acc[i][j][r] * alpha;
        int rg = m0 + wm + i * 16 + q * 4 + r;
        int cg = n0 + wn + j * 16 + l15;
        if (rg < Mw && cg < Nw) {
          long idx = zc + (long)rg * ldc + cg;
          if (om == 1) ((float*)(Cb + cb))[idx] = v;
          else if (om == 2) ((_Float16*)(Cb + cb))[idx] = (_Float16)v;
          else ((unsigned short*)(Cb + cb))[idx] = f2bf(v);
        }
        if (so >= 0 && rg < Mv && cg < Nv) { ssum += v; ssq += v * v; }
      }

  if (so >= 0) {
#pragma unroll
    for (int o = 32; o; o >>= 1) {
      ssum += __shfl_down(ssum, o, 64);
      ssq  += __shfl_down(ssq,  o, 64);
    }
    if (lane == 0) { red[wave] = ssum; red[wave + 4] = ssq; }
    __syncthreads();
    if (t == 0) {
      atomicAdd(stats + so + z * 2,     red[0] + red[1] + red[2] + red[3]);
      atomicAdd(stats + so + z * 2 + 1, red[4] + red[5] + red[6] + red[7]);
    }
  }
}

// ---------- 4-branch batched NT GEMM (128x128), branch from blockIdx.x ----------
struct MDesc {
  long aOff[4], bOff[4], cOff[4];
  long sAz[4], sBz[4], sCz[4];
  long iA[4], iB[4];
  int  lda[4], ldb[4], ldcv[4];
  int  Kk[4], Ncl[4], nIn[4];
  int  nstart[4];
  float alpha[4];
};

template<int OUT_F32>
__global__ __launch_bounds__(256)
void gemm_multi(const unsigned short* __restrict__ A0,
                const unsigned short* __restrict__ B0,
                void* __restrict__ Cp, MDesc d) {
  __shared__ unsigned short As[128 * 32];
  __shared__ unsigned short Bs[128 * 32];
  int bx = blockIdx.x;
  int br = (bx >= d.nstart[3]) ? 3 : (bx >= d.nstart[2]) ? 2 : (bx >= d.nstart[1]) ? 1 : 0;
  int z = blockIdx.z;
  int n0 = (bx - d.nstart[br]) * 128;
  int m0 = blockIdx.y * 128;
  int K = d.Kk[br], lda = d.lda[br], ldb = d.ldb[br], ldc = d.ldcv[br];
  int Ncl = d.Ncl[br], nInner = d.nIn[br];
  float alpha = d.alpha[br];
  const unsigned short* Ab = A0 + d.aOff[br] + (long)z * d.sAz[br];
  const unsigned short* Bb = B0 + d.bOff[br] + (long)z * d.sBz[br];

  int t = threadIdx.x, lane = t & 63, wave = t >> 6;
  int wm = (wave >> 1) * 64, wn = (wave & 1) * 64;
  int l15 = lane & 15, q = lane >> 4;
  int arow = t >> 2, acol = (t & 3) * 8;
  int rA0 = m0 + arow, rA1 = m0 + 64 + arow;
  int rB0 = min(n0 + arow, Ncl - 1), rB1 = min(n0 + 64 + arow, Ncl - 1);

  f32x4 acc[4][4] = {};
  for (int it = 0; it < nInner; ++it) {
    const unsigned short* Ait = Ab + (long)it * d.iA[br];
    const unsigned short* Bit = Bb + (long)it * d.iB[br];
    for (int k0 = 0; k0 < K; k0 += 32) {
      __syncthreads();
      __builtin_amdgcn_global_load_lds(
          (const __attribute__((address_space(1))) void*)(Ait + (long)rA0 * lda + acol + k0),
          (__attribute__((address_space(3))) void*)(As + t * 8), 16, 0, 0);
      __builtin_amdgcn_global_load_lds(
          (const __attribute__((address_space(1))) void*)(Ait + (long)rA1 * lda + acol + k0),
          (__attribute__((address_space(3))) void*)(As + 2048 + t * 8), 16, 0, 0);
      __builtin_amdgcn_global_load_lds(
          (const __attribute__((address_space(1))) void*)(Bit + (long)rB0 * ldb + acol + k0),
          (__attribute__((address_space(3))) void*)(Bs + t * 8), 16, 0, 0);
      __builtin_amdgcn_global_load_lds(
          (const __attribute__((address_space(1))) void*)(Bit + (long)rB1 * ldb + acol + k0),
          (__attribute__((address_space(3))) void*)(Bs + 2048 + t * 8), 16, 0, 0);
      __syncthreads();
      short8 af[4], bfr[4];
#pragma unroll
      for (int i = 0; i < 4; ++i)
        af[i] = *reinterpret_cast<const short8*>(As + (wm + i * 16 + l15) * 32 + q * 8);
#pragma unroll
      for (int j = 0; j < 4; ++j)
        bfr[j] = *reinterpret_cast<const short8*>(Bs + (wn + j * 16 + l15) * 32 + q * 8);
#pragma unroll
      for (int i = 0; i < 4; ++i)
#pragma unroll
        for (int j = 0; j < 4; ++j)
          acc[i][j] = __builtin_amdgcn_mfma_f32_16x16x32_bf16(af[i], bfr[j], acc[i][j], 0, 0, 0);
    }
  }

  long cb = d.cOff[br] + (long)z * d.sCz[br];
#pragma unroll
  for (int i = 0; i < 4; ++i)
#pragma unroll
    for (int j = 0; j < 4; ++j)
#pragma unroll
      for (int r = 0; r < 4; ++r) {
        float v = acc[i][j][r] * alpha;
        int rg = m0 + wm + i * 16 + q * 4 + r;
        int cg = n0 + wn + j * 16 + l15;
        if (cg < Ncl) {
          long idx = cb + (long)rg * ldc + cg;
          if (OUT_F32) ((float*)Cp)[idx] = v;
          else ((unsigned short*)Cp)[idx] = f2bf(v);
        }
      }
}

// ---------- batched instance-norm + softmax (fp16 in, ld 1024), bf16 out ----------
struct SD {
  long scOff[4];   // bytes into scratch
  long pOff[4];    // elements into arena U (probs dest)
  int  rowStart[5];
  int  C[4];
  int  stOff[4];
};

__global__ __launch_bounds__(256)
void softmax_multi(const char* __restrict__ Sb, unsigned short* __restrict__ U,
                   const float* __restrict__ stats, SD d) {
  const int KV = 960, LD = 1024;
  int row = blockIdx.x;
  int br = 0;
  while (row >= d.rowStart[br + 1]) ++br;
  int local = row - d.rowStart[br];
  int C = d.C[br];
  int bh = local / C;
  const _Float16* s = (const _Float16*)(Sb + d.scOff[br]) + (long)local * LD;
  unsigned short* P = U + d.pOff[br] + (long)local * LD;
  float invCnt = 1.0f / (float)(C * KV);
  float m1 = stats[d.stOff[br] + bh * 2 + 0] * invCnt;
  float m2 = stats[d.stOff[br] + bh * 2 + 1] * invCnt;
  float rsig = rsqrtf(m2 - m1 * m1 + 1e-5f);
  int t = threadIdx.x;
  float e[4]; float acc = 0.f;
#pragma unroll
  for (int j = 0; j < 4; ++j) {
    int i = t + j * 256;
    if (i < KV) { e[j] = __expf(((float)s[i] - m1) * rsig); acc += e[j]; }
    else e[j] = 0.f;
  }
#pragma unroll
  for (int o = 32; o; o >>= 1) acc += __shfl_down(acc, o, 64);
  __shared__ float red[4];
  if ((t & 63) == 0) red[t >> 6] = acc;
  __syncthreads();
  float inv = 1.0f / (red[0] + red[1] + red[2] + red[3]);
#pragma unroll
  for (int j = 0; j < 4; ++j) {
    int i = t + j * 256;
    if (i < KV) P[i] = f2bf(e[j] * inv);
  }
}

// ---------- host ----------
extern "C" void kernel_launch(void* const* d_in, const int* in_sizes, int n_in,
                              void* d_out, int out_size, void* d_ws, size_t ws_size,
                              hipStream_t stream) {
  const float* emb1 = (const float*)d_in[0];
  const float* emb2 = (const float*)d_in[1];
  const float* emb3 = (const float*)d_in[2];
  const float* emb4 = (const float*)d_in[3];
  const float* embA = (const float*)d_in[4];
  const float* Wq1  = (const float*)d_in[5];
  const float* Wq2  = (const float*)d_in[6];
  const float* Wq3  = (const float*)d_in[7];
  const float* Wq4  = (const float*)d_in[8];
  const float* Wk   = (const float*)d_in[9];
  const float* Wv   = (const float*)d_in[10];
  float* out = (float*)d_out;

  char* base = (char*)d_ws;
  unsigned short* U = (unsigned short*)d_ws;
  size_t off = 0;
  auto take = [&](size_t bytes) -> void* {
    void* p = base + off;
    off += (bytes + 255) & ~(size_t)255;
    return p;
  };
  unsigned short* Kt  = (unsigned short*)take(67108864);  // [b,h,1024(pad o),1024]; CT alias later
  unsigned short* Vb  = (unsigned short*)take(62914560);  // [b,h,1024,960]
  unsigned short* EB  = (unsigned short*)take(15728640);  // emb1..4 bf16
  unsigned short* WQb = (unsigned short*)take(2785280);
  unsigned short* WOb = (unsigned short*)take(696320);
  float*          ST  = (float*)take(1024);
  unsigned short* QTa = (unsigned short*)take(62914560);  // Q_all / probs (in place)
  char*           scratch = (char*)take(33554432);        // phase-A casts OR fp16 scores
  unsigned short* EA  = (unsigned short*)(scratch);              // 15,728,640
  unsigned short* WKb = (unsigned short*)(scratch + 15728640);   //  7,372,800
  unsigned short* WVb = (unsigned short*)(scratch + 23101440);   //  7,372,800
  unsigned short* CT  = Kt;  // ctx output aliases Kt (dead after scores)

  if (ws_size < off) return;  // fail clean instead of faulting

  hipMemsetAsync(ST, 0, 1024, stream);

  // casts (5 launches)
  cast4_kernel<<<4096, 256, 0, stream>>>(embA, 7864320, embA, 0, embA, 0, embA, 0, EA);
  cast4_kernel<<<4096, 256, 0, stream>>>(emb1, 524288, emb2, 1048576, emb3, 2097152, emb4, 4194304, EB);
  cast4_kernel<<<2048, 256, 0, stream>>>(Wk, 3686400, Wv, 3686400, Wk, 0, Wk, 0, WKb);
  cast4_kernel<<<1024, 256, 0, stream>>>(Wq1, 16384, Wq2, 65536, Wq3, 262144, Wq4, 1048576, WQb);
  cast4_kernel<<<512, 256, 0, stream>>>((const float*)d_in[11], 4096, (const float*)d_in[12], 16384,
                                        (const float*)d_in[13], 65536, (const float*)d_in[14], 262144, WOb);

  const long Cs[4]     = {64, 128, 256, 512};
  const long ebOff[4]  = {0, 524288, 1572864, 3670016};
  const long wqOff[4]  = {0, 16384, 81920, 344064};
  const long woOff[4]  = {0, 4096, 20480, 86016};
  const long outOff[4] = {0, 524288, 1572864, 3670016};
  const long qtOff[4]  = {0, 2097152, 6291456, 14680064};  // elems into QTa
  const float kscale = 0.0322748612f;  // 1/sqrt(960)

  // ---- K: Kt[b,h,o,n] = Wk[h] @ EA[b]^T, XCD-swizzled ----
  {
    GD d = {};
    d.aOff[0] = WKb - U; d.sAb[0] = 0; d.sAh[0] = 960L * 960; d.lda[0] = 960;
    d.bOff[0] = EA - U;  d.sBb[0] = 1024L * 960; d.sBh[0] = 0; d.ldb[0] = 960;
    d.cOff[0] = (char*)Kt - base; d.sC[0] = 1024L * 1024; d.ldc[0] = 1024;
    d.K[0] = 960; d.Hdiv[0] = 4; d.Mclamp[0] = 960; d.Nclamp[0] = 1024;
    d.Mwrite[0] = 1024; d.Nwrite[0] = 1024; d.outMode[0] = 0; d.statsOff[0] = -1;
    d.alpha[0] = 1.0f;
    int ys[5] = {0, 8, 8, 8, 8};
    for (int i = 0; i < 5; ++i) d.ystart[i] = ys[i];
    d.swiz = 1;
    gemm_mega<<<dim3(8, 8, 32), 256, 0, stream>>>(U, base, ST, d);
  }
  // ---- V: Vb[b,h,n,o] = EA[b] @ Wv[h]^T, XCD-swizzled ----
  {
    GD d = {};
    d.aOff[0] = EA - U;  d.sAb[0] = 1024L * 960; d.sAh[0] = 0; d.lda[0] = 960;
    d.bOff[0] = WVb - U; d.sBb[0] = 0; d.sBh[0] = 960L * 960; d.ldb[0] = 960;
    d.cOff[0] = (char*)Vb - base; d.sC[0] = 1024L * 960; d.ldc[0] = 960;
    d.K[0] = 960; d.Hdiv[0] = 4; d.Mclamp[0] = 1024; d.Nclamp[0] = 960;
    d.Mwrite[0] = 1024; d.Nwrite[0] = 960; d.outMode[0] = 0; d.statsOff[0] = -1;
    d.alpha[0] = 1.0f;
    int ys[5] = {0, 8, 8, 8, 8};
    for (int i = 0; i < 5; ++i) d.ystart[i] = ys[i];
    d.swiz = 1;
    gemm_mega<<<dim3(8, 8, 32), 256, 0, stream>>>(U, base, ST, d);
  }
  // ---- Q-all: Q_i[b,h,d,n] = Wq_i[h] @ emb_i[b]^T, 4 branches, one launch ----
  {
    GD d = {};
    for (int i = 0; i < 4; ++i) {
      long C = Cs[i];
      d.aOff[i] = (WQb - U) + wqOff[i]; d.sAb[i] = 0; d.sAh[i] = C * C; d.lda[i] = (int)C;
      d.bOff[i] = (EB - U) + ebOff[i];  d.sBb[i] = 1024L * C; d.sBh[i] = 0; d.ldb[i] = (int)C;
      d.cOff[i] = ((char*)QTa - base) + qtOff[i] * 2; d.sC[i] = C * 1024; d.ldc[i] = 1024;
      d.K[i] = (int)C; d.Hdiv[i] = 4; d.Mclamp[i] = (int)C; d.Nclamp[i] = 1024;
      d.Mwrite[i] = (int)C; d.Nwrite[i] = 1024; d.outMode[i] = 0; d.statsOff[i] = -1;
      d.alpha[i] = 1.0f;
    }
    int ys[5] = {0, 1, 2, 4, 8};  // C/128 ceil: 1,1,2,4
    for (int i = 0; i < 5; ++i) d.ystart[i] = ys[i];
    d.swiz = 0;
    gemm_mega<<<dim3(8, 8, 32), 256, 0, stream>>>(U, base, ST, d);
  }

  const long scOffA[3] = {0, 4194304, 12582912};  // fp16 score bytes: C=64,128,256

  // ---- scores-A: C=64,128,256 (+stats), XCD-swizzled ----
  {
    GD d = {};
    for (int i = 0; i < 3; ++i) {
      long C = Cs[i];
      d.aOff[i] = (QTa - U) + qtOff[i]; d.sAb[i] = 4L * C * 1024; d.sAh[i] = C * 1024;
      d.lda[i] = 1024;
      d.bOff[i] = Kt - U; d.sBb[i] = 4L * 1024 * 1024; d.sBh[i] = 1024L * 1024;
      d.ldb[i] = 1024;
      d.cOff[i] = (scratch - base) + scOffA[i]; d.sC[i] = C * 1024; d.ldc[i] = 1024;
      d.K[i] = 1024; d.Hdiv[i] = 4; d.Mclamp[i] = (int)C; d.Nclamp[i] = 1024;
      d.Mwrite[i] = (int)C; d.Nwrite[i] = 1024; d.outMode[i] = 2;
      d.statsOff[i] = i * 64; d.Mvalid[i] = (int)C; d.Nvalid[i] = 960;
      d.alpha[i] = kscale;
    }
    int ys[5] = {0, 1, 2, 4, 4};
    for (int i = 0; i < 5; ++i) d.ystart[i] = ys[i];
    d.swiz = 1;
    gemm_mega<<<dim3(8, 4, 32), 256, 0, stream>>>(U, base, ST, d);
  }
  // ---- softmax-A ----
  {
    SD s = {};
    int rs[5] = {0, 2048, 6144, 14336, 14336};
    for (int i = 0; i < 5; ++i) s.rowStart[i] = rs[i];
    for (int i = 0; i < 3; ++i) {
      s.scOff[i] = scOffA[i];
      s.pOff[i] = (QTa - U) + qtOff[i];
      s.C[i] = (int)Cs[i];
      s.stOff[i] = i * 64;
    }
    softmax_multi<<<dim3(14336), 256, 0, stream>>>(scratch, U, ST, s);
  }
  // ---- scores-B: C=512 (+stats), XCD-swizzled ----
  {
    GD d = {};
    long C = 512;
    d.aOff[0] = (QTa - U) + qtOff[3]; d.sAb[0] = 4L * C * 1024; d.sAh[0] = C * 1024;
    d.lda[0] = 1024;
    d.bOff[0] = Kt - U; d.sBb[0] = 4L * 1024 * 1024; d.sBh[0] = 1024L * 1024;
    d.ldb[0] = 1024;
    d.cOff[0] = (scratch - base); d.sC[0] = C * 1024; d.ldc[0] = 1024;
    d.K[0] = 1024; d.Hdiv[0] = 4; d.Mclamp[0] = (int)C; d.Nclamp[0] = 1024;
    d.Mwrite[0] = (int)C; d.Nwrite[0] = 1024; d.outMode[0] = 2;
    d.statsOff[0] = 192; d.Mvalid[0] = (int)C; d.Nvalid[0] = 960;
    d.alpha[0] = kscale;
    int ys[5] = {0, 4, 4, 4, 4};
    for (int i = 0; i < 5; ++i) d.ystart[i] = ys[i];
    d.swiz = 1;
    gemm_mega<<<dim3(8, 4, 32), 256, 0, stream>>>(U, base, ST, d);
  }
  // ---- softmax-B ----
  {
    SD s = {};
    int rs[5] = {0, 16384, 16384, 16384, 16384};
    for (int i = 0; i < 5; ++i) s.rowStart[i] = rs[i];
    s.scOff[0] = 0;
    s.pOff[0] = (QTa - U) + qtOff[3];
    s.C[0] = 512;
    s.stOff[0] = 192;
    softmax_multi<<<dim3(16384), 256, 0, stream>>>(scratch, U, ST, s);
  }

  // ---- ctx-all: CT[b,n,c] = (1/4) sum_h Vb[b,h] @ PR[b,h]^T ----
  {
    MDesc d;
    for (int i = 0; i < 4; ++i) {
      long C = Cs[i];
      d.aOff[i] = 0;            d.sAz[i] = 4L * 1024 * 960;  d.iA[i] = 1024L * 960;
      d.bOff[i] = qtOff[i];     d.sBz[i] = 4L * C * 1024;    d.iB[i] = C * 1024;
      d.cOff[i] = outOff[i];    d.sCz[i] = 1024L * C;
      d.lda[i] = 960; d.ldb[i] = 1024; d.ldcv[i] = (int)C;
      d.Kk[i] = 960; d.Ncl[i] = (int)C; d.nIn[i] = 4;
      d.alpha[i] = 0.25f;
    }
    d.nstart[0] = 0; d.nstart[1] = 1; d.nstart[2] = 2; d.nstart[3] = 4;
    gemm_multi<0><<<dim3(8, 8, 8), 256, 0, stream>>>(Vb, QTa, CT, d);
  }
  // ---- out-all: out[b,n,c'] = CT[b] @ Wo^T ----
  {
    MDesc d;
    for (int i = 0; i < 4; ++i) {
      long C = Cs[i];
      d.aOff[i] = outOff[i];    d.sAz[i] = 1024L * C;        d.iA[i] = 0;
      d.bOff[i] = woOff[i];     d.sBz[i] = 0;                d.iB[i] = 0;
      d.cOff[i] = outOff[i];    d.sCz[i] = 1024L * C;
      d.lda[i] = (int)C; d.ldb[i] = (int)C; d.ldcv[i] = (int)C;
      d.Kk[i] = (int)C; d.Ncl[i] = (int)C; d.nIn[i] = 1;
      d.alpha[i] = 1.0f;
    }
    d.nstart[0] = 0; d.nstart[1] = 1; d.nstart[2] = 2; d.nstart[3] = 4;
    gemm_multi<1><<<dim3(8, 8, 8), 256, 0, stream>>>(CT, WOb, out, d);
  }
  (void)in_sizes; (void)n_in; (void)out_size;
}

// Round 7
// 712.997 us; speedup vs baseline: 1.0332x; 1.0332x over previous
//
#include <hip/hip_runtime.h>
#include <hip/hip_bf16.h>

// ---------- types ----------
typedef __attribute__((ext_vector_type(8))) short short8;
typedef __attribute__((ext_vector_type(4))) float f32x4;

static __device__ __forceinline__ unsigned short f2bf(float x) {
  union { __hip_bfloat16 h; unsigned short u; } cv;
  cv.h = __float2bfloat16(x);
  return cv.u;
}

// ---------- fused cast fp32 -> bf16, 15 segments, one launch ----------
struct CD {
  const float* src[15];
  long dOff[15];   // element offset into arena U
  long cum[16];    // cumulative element counts (multiples of 4)
};

__global__ void cast_multi(CD d, unsigned short* __restrict__ U, long total4) {
  for (long i = blockIdx.x * (long)blockDim.x + threadIdx.x; i < total4;
       i += (long)gridDim.x * blockDim.x) {
    long e = i << 2;
    int s = 0;
    while (e >= d.cum[s + 1]) ++s;
    long j = e - d.cum[s];
    float4 v = *reinterpret_cast<const float4*>(d.src[s] + j);
    ushort4 o;
    o.x = f2bf(v.x); o.y = f2bf(v.y); o.z = f2bf(v.z); o.w = f2bf(v.w);
    *reinterpret_cast<ushort4*>(U + d.dOff[s] + j) = o;
  }
}

// ---------- generic NT bf16 MFMA GEMM, m97 structure, 128x128 tile ----------
__global__ __launch_bounds__(256)
void gemm_nt(const unsigned short* __restrict__ A,
             const unsigned short* __restrict__ B,
             void* __restrict__ Cp,
             int K, int lda, int ldb, long ldc, int Hdiv,
             long sAb, long sAh, long sBb, long sBh, long sC,
             int Mclamp, int Nclamp, int Nwrite) {
  __shared__ unsigned short As[128 * 32];
  __shared__ unsigned short Bs[128 * 32];

  int z = blockIdx.z;
  int b = z / Hdiv, h = z % Hdiv;
  const unsigned short* Ab = A + (long)b * sAb + (long)h * sAh;
  const unsigned short* Bb = B + (long)b * sBb + (long)h * sBh;
  int m0 = blockIdx.y * 128, n0 = blockIdx.x * 128;
  int t = threadIdx.x;
  int lane = t & 63, wave = t >> 6;
  int wm = (wave >> 1) * 64, wn = (wave & 1) * 64;
  int l15 = lane & 15, q = lane >> 4;
  int arow = t >> 2, acol = (t & 3) * 8;
  int rA0 = min(m0 + arow, Mclamp - 1), rA1 = min(m0 + 64 + arow, Mclamp - 1);
  int rB0 = min(n0 + arow, Nclamp - 1), rB1 = min(n0 + 64 + arow, Nclamp - 1);

  f32x4 acc[4][4] = {};
  for (int k0 = 0; k0 < K; k0 += 32) {
    __syncthreads();
    __builtin_amdgcn_global_load_lds(
        (const __attribute__((address_space(1))) void*)(Ab + (long)rA0 * lda + acol + k0),
        (__attribute__((address_space(3))) void*)(As + t * 8), 16, 0, 0);
    __builtin_amdgcn_global_load_lds(
        (const __attribute__((address_space(1))) void*)(Ab + (long)rA1 * lda + acol + k0),
        (__attribute__((address_space(3))) void*)(As + 2048 + t * 8), 16, 0, 0);
    __builtin_amdgcn_global_load_lds(
        (const __attribute__((address_space(1))) void*)(Bb + (long)rB0 * ldb + acol + k0),
        (__attribute__((address_space(3))) void*)(Bs + t * 8), 16, 0, 0);
    __builtin_amdgcn_global_load_lds(
        (const __attribute__((address_space(1))) void*)(Bb + (long)rB1 * ldb + acol + k0),
        (__attribute__((address_space(3))) void*)(Bs + 2048 + t * 8), 16, 0, 0);
    __syncthreads();
    short8 af[4], bfr[4];
#pragma unroll
    for (int i = 0; i < 4; ++i)
      af[i] = *reinterpret_cast<const short8*>(As + (wm + i * 16 + l15) * 32 + q * 8);
#pragma unroll
    for (int j = 0; j < 4; ++j)
      bfr[j] = *reinterpret_cast<const short8*>(Bs + (wn + j * 16 + l15) * 32 + q * 8);
#pragma unroll
    for (int i = 0; i < 4; ++i)
#pragma unroll
      for (int j = 0; j < 4; ++j)
        acc[i][j] = __builtin_amdgcn_mfma_f32_16x16x32_bf16(af[i], bfr[j], acc[i][j], 0, 0, 0);
  }

  long cbase = (long)z * sC;
#pragma unroll
  for (int i = 0; i < 4; ++i)
#pragma unroll
    for (int j = 0; j < 4; ++j)
#pragma unroll
      for (int r = 0; r < 4; ++r) {
        float v = acc[i][j][r];
        int rg = m0 + wm + i * 16 + q * 4 + r;
        int cg = n0 + wn + j * 16 + l15;
        if (cg < Nwrite)
          ((unsigned short*)Cp)[cbase + (long)rg * ldc + cg] = f2bf(v);
      }
}

// ---------- descriptor NT GEMM: up to 4 branches by blockIdx.y range ----------
struct GD {
  long aOff[4], bOff[4], cOff[4];
  long sAb[4], sAh[4], sBb[4], sBh[4];
  long sC[4], ldc[4];
  int  lda[4], ldb[4], K[4], Hdiv[4];
  int  Mclamp[4], Nclamp[4], Mwrite[4], Nwrite[4];
  int  outMode[4], statsOff[4], Mvalid[4], Nvalid[4];
  float alpha[4];
  int  ystart[5];
};

__global__ __launch_bounds__(256)
void gemm_mega(const unsigned short* __restrict__ U, char* __restrict__ Cb,
               float* __restrict__ stats, GD d) {
  __shared__ unsigned short As[128 * 32];
  __shared__ unsigned short Bs[128 * 32];
  __shared__ float red[8];

  int bx = blockIdx.x, ybl = blockIdx.y, z = blockIdx.z;
  int br = 0;
  while (ybl >= d.ystart[br + 1]) ++br;
  int m0 = (ybl - d.ystart[br]) * 128;
  int n0 = bx * 128;
  int Hd = d.Hdiv[br];
  int b = z / Hd, h = z - b * Hd;
  int K = d.K[br], lda = d.lda[br], ldb = d.ldb[br];
  const unsigned short* Ab = U + d.aOff[br] + (long)b * d.sAb[br] + (long)h * d.sAh[br];
  const unsigned short* Bb = U + d.bOff[br] + (long)b * d.sBb[br] + (long)h * d.sBh[br];

  int t = threadIdx.x, lane = t & 63, wave = t >> 6;
  int wm = (wave >> 1) * 64, wn = (wave & 1) * 64;
  int l15 = lane & 15, q = lane >> 4;
  int arow = t >> 2, acol = (t & 3) * 8;
  int rA0 = min(m0 + arow, d.Mclamp[br] - 1), rA1 = min(m0 + 64 + arow, d.Mclamp[br] - 1);
  int rB0 = min(n0 + arow, d.Nclamp[br] - 1), rB1 = min(n0 + 64 + arow, d.Nclamp[br] - 1);

  f32x4 acc[4][4] = {};
  for (int k0 = 0; k0 < K; k0 += 32) {
    __syncthreads();
    __builtin_amdgcn_global_load_lds(
        (const __attribute__((address_space(1))) void*)(Ab + (long)rA0 * lda + acol + k0),
        (__attribute__((address_space(3))) void*)(As + t * 8), 16, 0, 0);
    __builtin_amdgcn_global_load_lds(
        (const __attribute__((address_space(1))) void*)(Ab + (long)rA1 * lda + acol + k0),
        (__attribute__((address_space(3))) void*)(As + 2048 + t * 8), 16, 0, 0);
    __builtin_amdgcn_global_load_lds(
        (const __attribute__((address_space(1))) void*)(Bb + (long)rB0 * ldb + acol + k0),
        (__attribute__((address_space(3))) void*)(Bs + t * 8), 16, 0, 0);
    __builtin_amdgcn_global_load_lds(
        (const __attribute__((address_space(1))) void*)(Bb + (long)rB1 * ldb + acol + k0),
        (__attribute__((address_space(3))) void*)(Bs + 2048 + t * 8), 16, 0, 0);
    __syncthreads();
    short8 af[4], bfr[4];
#pragma unroll
    for (int i = 0; i < 4; ++i)
      af[i] = *reinterpret_cast<const short8*>(As + (wm + i * 16 + l15) * 32 + q * 8);
#pragma unroll
    for (int j = 0; j < 4; ++j)
      bfr[j] = *reinterpret_cast<const short8*>(Bs + (wn + j * 16 + l15) * 32 + q * 8);
#pragma unroll
    for (int i = 0; i < 4; ++i)
#pragma unroll
      for (int j = 0; j < 4; ++j)
        acc[i][j] = __builtin_amdgcn_mfma_f32_16x16x32_bf16(af[i], bfr[j], acc[i][j], 0, 0, 0);
  }

  float alpha = d.alpha[br];
  long cb = d.cOff[br];
  long ldc = d.ldc[br];
  long zc = (long)z * d.sC[br];
  int om = d.outMode[br];
  int Mw = d.Mwrite[br], Nw = d.Nwrite[br];
  int so = d.statsOff[br], Mv = d.Mvalid[br], Nv = d.Nvalid[br];
  float ssum = 0.f, ssq = 0.f;
#pragma unroll
  for (int i = 0; i < 4; ++i)
#pragma unroll
    for (int j = 0; j < 4; ++j)
#pragma unroll
      for (int r = 0; r < 4; ++r) {
        float v = acc[i][j][r] * alpha;
        int rg = m0 + wm + i * 16 + q * 4 + r;
        int cg = n0 + wn + j * 16 + l15;
        if (rg < Mw && cg < Nw) {
          long idx = zc + (long)rg * ldc + cg;
          if (om == 1) ((float*)(Cb + cb))[idx] = v;
          else if (om == 2) ((_Float16*)(Cb + cb))[idx] = (_Float16)v;
          else ((unsigned short*)(Cb + cb))[idx] = f2bf(v);
        }
        if (so >= 0 && rg < Mv && cg < Nv) { ssum += v; ssq += v * v; }
      }

  if (so >= 0) {
#pragma unroll
    for (int o = 32; o; o >>= 1) {
      ssum += __shfl_down(ssum, o, 64);
      ssq  += __shfl_down(ssq,  o, 64);
    }
    if (lane == 0) { red[wave] = ssum; red[wave + 4] = ssq; }
    __syncthreads();
    if (t == 0) {
      atomicAdd(stats + so + z * 2,     red[0] + red[1] + red[2] + red[3]);
      atomicAdd(stats + so + z * 2 + 1, red[4] + red[5] + red[6] + red[7]);
    }
  }
}

// ---------- 4-branch batched NT GEMM (128x128), branch from blockIdx.x ----------
struct MDesc {
  long aOff[4], bOff[4], cOff[4];
  long sAz[4], sBz[4], sCz[4];
  long iA[4], iB[4];
  int  lda[4], ldb[4], ldcv[4];
  int  Kk[4], Ncl[4], nIn[4];
  int  nstart[4];
  float alpha[4];
};

template<int OUT_F32>
__global__ __launch_bounds__(256)
void gemm_multi(const unsigned short* __restrict__ A0,
                const unsigned short* __restrict__ B0,
                void* __restrict__ Cp, MDesc d) {
  __shared__ unsigned short As[128 * 32];
  __shared__ unsigned short Bs[128 * 32];
  int bx = blockIdx.x;
  int br = (bx >= d.nstart[3]) ? 3 : (bx >= d.nstart[2]) ? 2 : (bx >= d.nstart[1]) ? 1 : 0;
  int z = blockIdx.z;
  int n0 = (bx - d.nstart[br]) * 128;
  int m0 = blockIdx.y * 128;
  int K = d.Kk[br], lda = d.lda[br], ldb = d.ldb[br], ldc = d.ldcv[br];
  int Ncl = d.Ncl[br], nInner = d.nIn[br];
  float alpha = d.alpha[br];
  const unsigned short* Ab = A0 + d.aOff[br] + (long)z * d.sAz[br];
  const unsigned short* Bb = B0 + d.bOff[br] + (long)z * d.sBz[br];

  int t = threadIdx.x, lane = t & 63, wave = t >> 6;
  int wm = (wave >> 1) * 64, wn = (wave & 1) * 64;
  int l15 = lane & 15, q = lane >> 4;
  int arow = t >> 2, acol = (t & 3) * 8;
  int rA0 = m0 + arow, rA1 = m0 + 64 + arow;
  int rB0 = min(n0 + arow, Ncl - 1), rB1 = min(n0 + 64 + arow, Ncl - 1);

  f32x4 acc[4][4] = {};
  for (int it = 0; it < nInner; ++it) {
    const unsigned short* Ait = Ab + (long)it * d.iA[br];
    const unsigned short* Bit = Bb + (long)it * d.iB[br];
    for (int k0 = 0; k0 < K; k0 += 32) {
      __syncthreads();
      __builtin_amdgcn_global_load_lds(
          (const __attribute__((address_space(1))) void*)(Ait + (long)rA0 * lda + acol + k0),
          (__attribute__((address_space(3))) void*)(As + t * 8), 16, 0, 0);
      __builtin_amdgcn_global_load_lds(
          (const __attribute__((address_space(1))) void*)(Ait + (long)rA1 * lda + acol + k0),
          (__attribute__((address_space(3))) void*)(As + 2048 + t * 8), 16, 0, 0);
      __builtin_amdgcn_global_load_lds(
          (const __attribute__((address_space(1))) void*)(Bit + (long)rB0 * ldb + acol + k0),
          (__attribute__((address_space(3))) void*)(Bs + t * 8), 16, 0, 0);
      __builtin_amdgcn_global_load_lds(
          (const __attribute__((address_space(1))) void*)(Bit + (long)rB1 * ldb + acol + k0),
          (__attribute__((address_space(3))) void*)(Bs + 2048 + t * 8), 16, 0, 0);
      __syncthreads();
      short8 af[4], bfr[4];
#pragma unroll
      for (int i = 0; i < 4; ++i)
        af[i] = *reinterpret_cast<const short8*>(As + (wm + i * 16 + l15) * 32 + q * 8);
#pragma unroll
      for (int j = 0; j < 4; ++j)
        bfr[j] = *reinterpret_cast<const short8*>(Bs + (wn + j * 16 + l15) * 32 + q * 8);
#pragma unroll
      for (int i = 0; i < 4; ++i)
#pragma unroll
        for (int j = 0; j < 4; ++j)
          acc[i][j] = __builtin_amdgcn_mfma_f32_16x16x32_bf16(af[i], bfr[j], acc[i][j], 0, 0, 0);
    }
  }

  long cb = d.cOff[br] + (long)z * d.sCz[br];
#pragma unroll
  for (int i = 0; i < 4; ++i)
#pragma unroll
    for (int j = 0; j < 4; ++j)
#pragma unroll
      for (int r = 0; r < 4; ++r) {
        float v = acc[i][j][r] * alpha;
        int rg = m0 + wm + i * 16 + q * 4 + r;
        int cg = n0 + wn + j * 16 + l15;
        if (cg < Ncl) {
          long idx = cb + (long)rg * ldc + cg;
          if (OUT_F32) ((float*)Cp)[idx] = v;
          else ((unsigned short*)Cp)[idx] = f2bf(v);
        }
      }
}

// ---------- batched instance-norm + softmax (fp16 in, ld 1024), bf16 out ----------
struct SD {
  long scOff[4];   // bytes into scratch
  long pOff[4];    // elements into arena U (probs dest)
  int  rowStart[5];
  int  C[4];
  int  stOff[4];
};

__global__ __launch_bounds__(256)
void softmax_multi(const char* __restrict__ Sb, unsigned short* __restrict__ U,
                   const float* __restrict__ stats, SD d) {
  const int KV = 960, LD = 1024;
  int row = blockIdx.x;
  int br = 0;
  while (row >= d.rowStart[br + 1]) ++br;
  int local = row - d.rowStart[br];
  int C = d.C[br];
  int bh = local / C;
  const _Float16* s = (const _Float16*)(Sb + d.scOff[br]) + (long)local * LD;
  unsigned short* P = U + d.pOff[br] + (long)local * LD;
  float invCnt = 1.0f / (float)(C * KV);
  float m1 = stats[d.stOff[br] + bh * 2 + 0] * invCnt;
  float m2 = stats[d.stOff[br] + bh * 2 + 1] * invCnt;
  float rsig = rsqrtf(m2 - m1 * m1 + 1e-5f);
  int t = threadIdx.x;
  float e[4]; float acc = 0.f;
#pragma unroll
  for (int j = 0; j < 4; ++j) {
    int i = t + j * 256;
    if (i < KV) { e[j] = __expf(((float)s[i] - m1) * rsig); acc += e[j]; }
    else e[j] = 0.f;
  }
#pragma unroll
  for (int o = 32; o; o >>= 1) acc += __shfl_down(acc, o, 64);
  __shared__ float red[4];
  if ((t & 63) == 0) red[t >> 6] = acc;
  __syncthreads();
  float inv = 1.0f / (red[0] + red[1] + red[2] + red[3]);
#pragma unroll
  for (int j = 0; j < 4; ++j) {
    int i = t + j * 256;
    if (i < KV) P[i] = f2bf(e[j] * inv);
  }
}

// ---------- host ----------
extern "C" void kernel_launch(void* const* d_in, const int* in_sizes, int n_in,
                              void* d_out, int out_size, void* d_ws, size_t ws_size,
                              hipStream_t stream) {
  float* out = (float*)d_out;

  char* base = (char*)d_ws;
  unsigned short* U = (unsigned short*)d_ws;
  size_t off = 0;
  auto take = [&](size_t bytes) -> void* {
    void* p = base + off;
    off += (bytes + 255) & ~(size_t)255;
    return p;
  };
  unsigned short* Kt  = (unsigned short*)take(67108864);  // [b,h,1024(pad o),1024]; CT alias later
  unsigned short* Vb  = (unsigned short*)take(62914560);  // [b,h,1024,960]
  unsigned short* EB  = (unsigned short*)take(15728640);  // emb1..4 bf16
  unsigned short* WQb = (unsigned short*)take(2785280);
  unsigned short* WOb = (unsigned short*)take(696320);
  float*          ST  = (float*)take(1024);
  unsigned short* QTa = (unsigned short*)take(62914560);  // Q_all / probs (in place)
  char*           scratch = (char*)take(33554432);        // phase-A casts OR fp16 scores
  unsigned short* EA  = (unsigned short*)(scratch);              // 15,728,640 B
  unsigned short* WKb = (unsigned short*)(scratch + 15728640);   //  7,372,800 B
  unsigned short* WVb = (unsigned short*)(scratch + 23101440);   //  7,372,800 B
  unsigned short* CT  = Kt;  // ctx output aliases Kt (dead after scores)

  if (ws_size < off) return;  // fail clean instead of faulting

  hipMemsetAsync(ST, 0, 1024, stream);

  const long Cs[4]     = {64, 128, 256, 512};
  const long ebOff[4]  = {0, 524288, 1572864, 3670016};
  const long wqOff[4]  = {0, 16384, 81920, 344064};
  const long woOff[4]  = {0, 4096, 20480, 86016};
  const long outOff[4] = {0, 524288, 1572864, 3670016};
  const long qtOff[4]  = {0, 2097152, 6291456, 14680064};  // elems into QTa
  const float kscale = 0.0322748612f;  // 1/sqrt(960)

  // ---- fused casts: 15 segments, one launch ----
  {
    CD c;
    const float* srcs[15] = {
      (const float*)d_in[4],                                    // embA
      (const float*)d_in[0], (const float*)d_in[1],
      (const float*)d_in[2], (const float*)d_in[3],             // emb1..4
      (const float*)d_in[9], (const float*)d_in[10],            // Wk, Wv
      (const float*)d_in[5], (const float*)d_in[6],
      (const float*)d_in[7], (const float*)d_in[8],             // Wq1..4
      (const float*)d_in[11], (const float*)d_in[12],
      (const float*)d_in[13], (const float*)d_in[14]            // Wo1..4
    };
    long cnt[15] = {7864320, 524288, 1048576, 2097152, 4194304,
                    3686400, 3686400, 16384, 65536, 262144, 1048576,
                    4096, 16384, 65536, 262144};
    long dsts[15] = {
      EA - U,
      (EB - U) + ebOff[0], (EB - U) + ebOff[1], (EB - U) + ebOff[2], (EB - U) + ebOff[3],
      WKb - U, WVb - U,
      (WQb - U) + wqOff[0], (WQb - U) + wqOff[1], (WQb - U) + wqOff[2], (WQb - U) + wqOff[3],
      (WOb - U) + woOff[0], (WOb - U) + woOff[1], (WOb - U) + woOff[2], (WOb - U) + woOff[3]
    };
    long cum = 0;
    for (int i = 0; i < 15; ++i) {
      c.src[i] = srcs[i]; c.dOff[i] = dsts[i]; c.cum[i] = cum; cum += cnt[i];
    }
    c.cum[15] = cum;
    cast_multi<<<dim3(8192), 256, 0, stream>>>(c, U, cum >> 2);
  }

  // ---- K: Kt[b,h,o,n] = Wk[h] @ EA[b]^T : M=1024(pad, clamp 960), N=1024, K=960 ----
  gemm_nt<<<dim3(8, 8, 32), 256, 0, stream>>>(
      WKb, EA, Kt, 960, 960, 960, 1024, 4,
      0L, 960L * 960, 1024L * 960, 0L, 1024L * 1024,
      960, 1024, 1024);
  // ---- V: Vb[b,h,n,o] = EA[b] @ Wv[h]^T : M=1024, N=1024(pad, write<960), K=960 ----
  gemm_nt<<<dim3(8, 8, 32), 256, 0, stream>>>(
      EA, WVb, Vb, 960, 960, 960, 960, 4,
      1024L * 960, 0L, 0L, 960L * 960, 1024L * 960,
      1024, 960, 960);

  // ---- Q-all: Q_i[b,h,d,n] = Wq_i[h] @ emb_i[b]^T, 4 branches, one launch ----
  {
    GD d = {};
    for (int i = 0; i < 4; ++i) {
      long C = Cs[i];
      d.aOff[i] = (WQb - U) + wqOff[i]; d.sAb[i] = 0; d.sAh[i] = C * C; d.lda[i] = (int)C;
      d.bOff[i] = (EB - U) + ebOff[i];  d.sBb[i] = 1024L * C; d.sBh[i] = 0; d.ldb[i] = (int)C;
      d.cOff[i] = ((char*)QTa - base) + qtOff[i] * 2; d.sC[i] = C * 1024; d.ldc[i] = 1024;
      d.K[i] = (int)C; d.Hdiv[i] = 4; d.Mclamp[i] = (int)C; d.Nclamp[i] = 1024;
      d.Mwrite[i] = (int)C; d.Nwrite[i] = 1024; d.outMode[i] = 0; d.statsOff[i] = -1;
      d.alpha[i] = 1.0f;
    }
    int ys[5] = {0, 1, 2, 4, 8};
    for (int i = 0; i < 5; ++i) d.ystart[i] = ys[i];
    gemm_mega<<<dim3(8, 8, 32), 256, 0, stream>>>(U, base, ST, d);
  }

  const long scOffA[3] = {0, 4194304, 12582912};  // fp16 score bytes: C=64,128,256

  // ---- scores-A: C=64,128,256 (+stats) ----
  {
    GD d = {};
    for (int i = 0; i < 3; ++i) {
      long C = Cs[i];
      d.aOff[i] = (QTa - U) + qtOff[i]; d.sAb[i] = 4L * C * 1024; d.sAh[i] = C * 1024;
      d.lda[i] = 1024;
      d.bOff[i] = Kt - U; d.sBb[i] = 4L * 1024 * 1024; d.sBh[i] = 1024L * 1024;
      d.ldb[i] = 1024;
      d.cOff[i] = (scratch - base) + scOffA[i]; d.sC[i] = C * 1024; d.ldc[i] = 1024;
      d.K[i] = 1024; d.Hdiv[i] = 4; d.Mclamp[i] = (int)C; d.Nclamp[i] = 1024;
      d.Mwrite[i] = (int)C; d.Nwrite[i] = 1024; d.outMode[i] = 2;
      d.statsOff[i] = i * 64; d.Mvalid[i] = (int)C; d.Nvalid[i] = 960;
      d.alpha[i] = kscale;
    }
    int ys[5] = {0, 1, 2, 4, 4};
    for (int i = 0; i < 5; ++i) d.ystart[i] = ys[i];
    gemm_mega<<<dim3(8, 4, 32), 256, 0, stream>>>(U, base, ST, d);
  }
  // ---- softmax-A ----
  {
    SD s = {};
    int rs[5] = {0, 2048, 6144, 14336, 14336};
    for (int i = 0; i < 5; ++i) s.rowStart[i] = rs[i];
    for (int i = 0; i < 3; ++i) {
      s.scOff[i] = scOffA[i];
      s.pOff[i] = (QTa - U) + qtOff[i];
      s.C[i] = (int)Cs[i];
      s.stOff[i] = i * 64;
    }
    softmax_multi<<<dim3(14336), 256, 0, stream>>>(scratch, U, ST, s);
  }
  // ---- scores-B: C=512 (+stats) ----
  {
    GD d = {};
    long C = 512;
    d.aOff[0] = (QTa - U) + qtOff[3]; d.sAb[0] = 4L * C * 1024; d.sAh[0] = C * 1024;
    d.lda[0] = 1024;
    d.bOff[0] = Kt - U; d.sBb[0] = 4L * 1024 * 1024; d.sBh[0] = 1024L * 1024;
    d.ldb[0] = 1024;
    d.cOff[0] = (scratch - base); d.sC[0] = C * 1024; d.ldc[0] = 1024;
    d.K[0] = 1024; d.Hdiv[0] = 4; d.Mclamp[0] = (int)C; d.Nclamp[0] = 1024;
    d.Mwrite[0] = (int)C; d.Nwrite[0] = 1024; d.outMode[0] = 2;
    d.statsOff[0] = 192; d.Mvalid[0] = (int)C; d.Nvalid[0] = 960;
    d.alpha[0] = kscale;
    int ys[5] = {0, 4, 4, 4, 4};
    for (int i = 0; i < 5; ++i) d.ystart[i] = ys[i];
    gemm_mega<<<dim3(8, 4, 32), 256, 0, stream>>>(U, base, ST, d);
  }
  // ---- softmax-B ----
  {
    SD s = {};
    int rs[5] = {0, 16384, 16384, 16384, 16384};
    for (int i = 0; i < 5; ++i) s.rowStart[i] = rs[i];
    s.scOff[0] = 0;
    s.pOff[0] = (QTa - U) + qtOff[3];
    s.C[0] = 512;
    s.stOff[0] = 192;
    softmax_multi<<<dim3(16384), 256, 0, stream>>>(scratch, U, ST, s);
  }

  // ---- ctx-all: CT[b,n,c] = (1/4) sum_h Vb[b,h] @ PR[b,h]^T ----
  {
    MDesc d;
    for (int i = 0; i < 4; ++i) {
      long C = Cs[i];
      d.aOff[i] = 0;            d.sAz[i] = 4L * 1024 * 960;  d.iA[i] = 1024L * 960;
      d.bOff[i] = qtOff[i];     d.sBz[i] = 4L * C * 1024;    d.iB[i] = C * 1024;
      d.cOff[i] = outOff[i];    d.sCz[i] = 1024L * C;
      d.lda[i] = 960; d.ldb[i] = 1024; d.ldcv[i] = (int)C;
      d.Kk[i] = 960; d.Ncl[i] = (int)C; d.nIn[i] = 4;
      d.alpha[i] = 0.25f;
    }
    d.nstart[0] = 0; d.nstart[1] = 1; d.nstart[2] = 2; d.nstart[3] = 4;
    gemm_multi<0><<<dim3(8, 8, 8), 256, 0, stream>>>(Vb, QTa, CT, d);
  }
  // ---- out-all: out[b,n,c'] = CT[b] @ Wo^T ----
  {
    MDesc d;
    for (int i = 0; i < 4; ++i) {
      long C = Cs[i];
      d.aOff[i] = outOff[i];    d.sAz[i] = 1024L * C;        d.iA[i] = 0;
      d.bOff[i] = woOff[i];     d.sBz[i] = 0;                d.iB[i] = 0;
      d.cOff[i] = outOff[i];    d.sCz[i] = 1024L * C;
      d.lda[i] = (int)C; d.ldb[i] = (int)C; d.ldcv[i] = (int)C;
      d.Kk[i] = (int)C; d.Ncl[i] = (int)C; d.nIn[i] = 1;
      d.alpha[i] = 1.0f;
    }
    d.nstart[0] = 0; d.nstart[1] = 1; d.nstart[2] = 2; d.nstart[3] = 4;
    gemm_multi<1><<<dim3(8, 8, 8), 256, 0, stream>>>(CT, WOb, out, d);
  }
  (void)in_sizes; (void)n_in; (void)out_size;
}